// Round 1
// baseline (170.197 us; speedup 1.0000x reference)
//
#include <hip/hip_runtime.h>
#include <math.h>

#define KK 5
#define KP 125          // 5*5*5
#define FPB 2           // filters per block
#define TPF 128         // threads per filter (125 active)

__global__ __launch_bounds__(FPB * TPF) void fastrot_kernel(
    const float* __restrict__ vol,      // N * 125
    const float* __restrict__ theta_v,  // N * 3
    const float* __restrict__ theta,    // N
    float* __restrict__ out)            // N * 125
{
    __shared__ float sv[FPB][KP];

    const int t = threadIdx.x;
    const int f = t >> 7;        // filter slot within block
    const int p = t & 127;       // point index within filter
    const long long n = (long long)blockIdx.x * FPB + f;

    // ---- stage volume into LDS (coalesced) ----
    if (p < KP) {
        sv[f][p] = vol[n * KP + p];
    }

    // ---- Rodrigues rotation matrix (redundant per thread; cheap) ----
    const float ax = theta_v[n * 3 + 0];
    const float ay = theta_v[n * 3 + 1];
    const float az = theta_v[n * 3 + 2];
    const float th = theta[n];

    const float nrm = sqrtf(ax * ax + ay * ay + az * az);
    const float inv = 1.0f / fmaxf(nrm, 1e-12f);
    const float vx = ax * inv, vy = ay * inv, vz = az * inv;

    const float s = __sinf(th);
    const float c = 1.0f - __cosf(th);

    // R = I + s*m + c*(m@m), m = skew(v)
    const float R00 = 1.0f - c * (vy * vy + vz * vz);
    const float R01 = -s * vz + c * (vx * vy);
    const float R02 =  s * vy + c * (vx * vz);
    const float R10 =  s * vz + c * (vx * vy);
    const float R11 = 1.0f - c * (vx * vx + vz * vz);
    const float R12 = -s * vx + c * (vy * vz);
    const float R20 = -s * vy + c * (vx * vz);
    const float R21 =  s * vx + c * (vy * vz);
    const float R22 = 1.0f - c * (vx * vx + vy * vy);

    __syncthreads();

    if (p < KP) {
        // base grid point: p = i*25 + j*5 + l, coords c[t] = -1 + 0.5*t
        const int i = p / 25;
        const int j = (p / 5) % 5;
        const int l = p % 5;
        const float b0 = -1.0f + 0.5f * (float)i;
        const float b1 = -1.0f + 0.5f * (float)j;
        const float b2 = -1.0f + 0.5f * (float)l;

        // grids[n,p,k] = sum_j base[p,j] * R[n,j,k]
        const float gx = b0 * R00 + b1 * R10 + b2 * R20;
        const float gy = b0 * R01 + b1 * R11 + b2 * R21;
        const float gz = b0 * R02 + b1 * R12 + b2 * R22;

        // map to voxel coords: (g+1)*0.5*(dim-1), dim=5 -> *2
        const float x = (gx + 1.0f) * 2.0f;
        const float y = (gy + 1.0f) * 2.0f;
        const float z = (gz + 1.0f) * 2.0f;

        const float x0f = floorf(x), y0f = floorf(y), z0f = floorf(z);
        const float wx = x - x0f, wy = y - y0f, wz = z - z0f;
        const int x0 = (int)x0f, y0 = (int)y0f, z0 = (int)z0f;

        float acc = 0.0f;
#pragma unroll
        for (int dz = 0; dz < 2; ++dz) {
#pragma unroll
            for (int dy = 0; dy < 2; ++dy) {
#pragma unroll
                for (int dx = 0; dx < 2; ++dx) {
                    const int zi = z0 + dz, yi = y0 + dy, xi = x0 + dx;
                    const float w = (dz ? wz : 1.0f - wz) *
                                    (dy ? wy : 1.0f - wy) *
                                    (dx ? wx : 1.0f - wx);
                    const bool inb = (zi >= 0) & (zi < KK) &
                                     (yi >= 0) & (yi < KK) &
                                     (xi >= 0) & (xi < KK);
                    const int ci = min(max(zi, 0), KK - 1) * 25 +
                                   min(max(yi, 0), KK - 1) * 5 +
                                   min(max(xi, 0), KK - 1);
                    const float v = sv[f][ci];
                    acc += inb ? (w * v) : 0.0f;
                }
            }
        }
        out[n * KP + p] = acc;
    }
}

extern "C" void kernel_launch(void* const* d_in, const int* in_sizes, int n_in,
                              void* d_out, int out_size, void* d_ws, size_t ws_size,
                              hipStream_t stream) {
    const float* vol     = (const float*)d_in[0];  // input_filter: N*125
    const float* theta_v = (const float*)d_in[1];  // N*3
    const float* theta   = (const float*)d_in[2];  // N
    float* out           = (float*)d_out;

    const int N = in_sizes[2];           // 262144
    const int grid = N / FPB;            // N is even; exact

    fastrot_kernel<<<grid, FPB * TPF, 0, stream>>>(vol, theta_v, theta, out);
}

// Round 2
// 87.605 us; speedup vs baseline: 1.9428x; 1.9428x over previous
//
#include <hip/hip_runtime.h>
#include <math.h>

#define KP   125        // 5*5*5 filter taps
#define PADF 736        // 9*9*9 = 729 zero-padded volume, rounded up to /4

// One wave (64 lanes) per filter; 2 points per lane; 4 filters per 256-thread block.
__global__ __launch_bounds__(256) void fastrot_kernel(
    const float* __restrict__ vol,      // N*125
    const float* __restrict__ theta_v,  // N*3
    const float* __restrict__ theta,    // N
    float* __restrict__ out)            // N*125
{
    __shared__ float pad[4][PADF];

    const int lane = threadIdx.x & 63;
    const int wv   = threadIdx.x >> 6;
    const long long n = (long long)blockIdx.x * 4 + wv;

    // ---- zero-fill padded volume (float4 LDS writes: 184 per filter) ----
    float4* p4 = (float4*)(&pad[wv][0]);
    const float4 z4 = make_float4(0.f, 0.f, 0.f, 0.f);
    p4[lane]      = z4;
    p4[lane + 64] = z4;
    if (lane < PADF / 4 - 128) p4[lane + 128] = z4;

    // ---- load this filter's 125 values: 2 coalesced loads per lane ----
    const float* vn = vol + n * (long long)KP;
    const int p0 = lane;
    const int p1 = lane + 64;
    const float fv0 = vn[p0];
    const float fv1 = (p1 < KP) ? vn[p1] : 0.0f;

    // decompose p -> (i,j,l): i = D(z) idx, j = H(y), l = W(x)
    // exact magic-mul for p < 128: /25 = *41>>10, /5 = *205>>10
    const int i0 = (p0 * 41) >> 10;
    const int q0 = (p0 * 205) >> 10;
    const int j0 = q0 - i0 * 5;
    const int l0 = p0 - q0 * 5;
    const int i1 = (p1 * 41) >> 10;
    const int q1 = (p1 * 205) >> 10;
    const int j1 = q1 - i1 * 5;
    const int l1 = p1 - q1 * 5;

    __syncthreads();   // fill done (avoid write-write hazard with scatter)

    // ---- scatter interior: padded idx = z*81 + y*9 + x + 182 ----
    pad[wv][i0 * 81 + j0 * 9 + l0 + 182] = fv0;
    if (p1 < KP) pad[wv][i1 * 81 + j1 * 9 + l1 + 182] = fv1;

    // ---- Rodrigues (wave-uniform; amortized over 2 points/lane) ----
    const float ax = theta_v[n * 3 + 0];
    const float ay = theta_v[n * 3 + 1];
    const float az = theta_v[n * 3 + 2];
    const float th = theta[n];
    const float d2  = ax * ax + ay * ay + az * az;
    const float inv = rsqrtf(fmaxf(d2, 1e-24f));   // == 1/max(|v|,1e-12) here
    const float vx = ax * inv, vy = ay * inv, vz = az * inv;
    float s, cth;
    __sincosf(th, &s, &cth);
    const float c = 1.0f - cth;

    const float R00 = 1.0f - c * (vy * vy + vz * vz);
    const float R01 = -s * vz + c * (vx * vy);
    const float R02 =  s * vy + c * (vx * vz);
    const float R10 =  s * vz + c * (vx * vy);
    const float R11 = 1.0f - c * (vx * vx + vz * vz);
    const float R12 = -s * vx + c * (vy * vz);
    const float R20 = -s * vy + c * (vx * vz);
    const float R21 =  s * vx + c * (vy * vz);
    const float R22 = 1.0f - c * (vx * vx + vy * vy);

    __syncthreads();   // scatter done

    const float* pw = &pad[wv][0];
    float* on = out + n * (long long)KP;

    // voxel coord: x = (gx+1)*2 = (i-2)*R00 + (j-2)*R10 + (l-2)*R20 + 2
    // (2*base == integer i-2). floor in [-2,5] guaranteed (|g| <= sqrt3),
    // so the 9^3 pad needs no clamps or bounds checks.
    auto sample = [&](int bi, int bj, int bl) -> float {
        const float Bi = (float)(bi - 2);
        const float Bj = (float)(bj - 2);
        const float Bl = (float)(bl - 2);
        const float x = fmaf(Bi, R00, fmaf(Bj, R10, fmaf(Bl, R20, 2.0f)));
        const float y = fmaf(Bi, R01, fmaf(Bj, R11, fmaf(Bl, R21, 2.0f)));
        const float z = fmaf(Bi, R02, fmaf(Bj, R12, fmaf(Bl, R22, 2.0f)));
        const float xf = floorf(x), yf = floorf(y), zf = floorf(z);
        const float wx = x - xf,   wy = y - yf,   wz = z - zf;
        const int x0 = (int)xf, y0 = (int)yf, z0 = (int)zf;
        const int ci = z0 * 81 + y0 * 9 + x0 + 182;   // in [0, 637]

        const float ux = 1.0f - wx, uy = 1.0f - wy, uz = 1.0f - wz;
        const float w00 = uz * uy, w01 = uz * wy, w10 = wz * uy, w11 = wz * wy;

        // adjacent-dword pairs -> ds_read2_b32
        const float a00 = pw[ci],      a01 = pw[ci + 1];
        const float a10 = pw[ci + 9],  a11 = pw[ci + 10];
        const float a20 = pw[ci + 81], a21 = pw[ci + 82];
        const float a30 = pw[ci + 90], a31 = pw[ci + 91];

        const float r0 = fmaf(wx, a01, ux * a00);
        const float r1 = fmaf(wx, a11, ux * a10);
        const float r2 = fmaf(wx, a21, ux * a20);
        const float r3 = fmaf(wx, a31, ux * a30);
        return fmaf(w00, r0, fmaf(w01, r1, fmaf(w10, r2, w11 * r3)));
    };

    on[p0] = sample(i0, j0, l0);
    if (p1 < KP) on[p1] = sample(i1, j1, l1);
}

extern "C" void kernel_launch(void* const* d_in, const int* in_sizes, int n_in,
                              void* d_out, int out_size, void* d_ws, size_t ws_size,
                              hipStream_t stream) {
    const float* vol     = (const float*)d_in[0];
    const float* theta_v = (const float*)d_in[1];
    const float* theta   = (const float*)d_in[2];
    float* out           = (float*)d_out;

    const int N = in_sizes[2];          // 262144, divisible by 4
    fastrot_kernel<<<N / 4, 256, 0, stream>>>(vol, theta_v, theta, out);
}

// Round 3
// 74.789 us; speedup vs baseline: 2.2757x; 1.1714x over previous
//
#include <hip/hip_runtime.h>
#include <math.h>

#define KP   125        // 5*5*5 filter taps
#define PADF 736        // 9*9*9 = 729 zero-padded volume, rounded to /4
#define FPB  8          // filters per block == waves per block

__global__ __launch_bounds__(FPB * 64) void fastrot_kernel(
    const float* __restrict__ vol,      // N*125
    const float* __restrict__ theta_v,  // N*3
    const float* __restrict__ theta,    // N
    float* __restrict__ out)            // N*125
{
    __shared__ __align__(16) float pad[FPB][PADF];
    __shared__ float4 sR4[FPB][4];      // 9 floats of R per filter (16B aligned)

    const int lane = threadIdx.x & 63;
    const int wv   = threadIdx.x >> 6;
    const long long nb = (long long)blockIdx.x * FPB;
    const long long n  = nb + wv;

    // ---- zero-fill padded volume (float4 LDS writes) ----
    float4* p4 = (float4*)(&pad[wv][0]);
    const float4 z4 = make_float4(0.f, 0.f, 0.f, 0.f);
    p4[lane]      = z4;
    p4[lane + 64] = z4;
    if (lane < PADF / 4 - 128) p4[lane + 128] = z4;

    // ---- load this filter's 125 values (coalesced) ----
    const float* vn = vol + n * (long long)KP;
    const int p0 = lane;
    const int p1 = lane + 64;
    const float fv0 = vn[p0];
    const float fv1 = (p1 < KP) ? vn[p1] : 0.0f;

    // p -> (i,j,l) via exact magic-mul for p < 128
    const int i0 = (p0 * 41) >> 10;
    const int q0 = (p0 * 205) >> 10;
    const int j0 = q0 - i0 * 5;
    const int l0 = p0 - q0 * 5;
    const int i1 = (p1 * 41) >> 10;
    const int q1 = (p1 * 205) >> 10;
    const int j1 = q1 - i1 * 5;
    const int l1 = p1 - q1 * 5;

    // ---- wave 0 computes Rodrigues for all FPB filters (amortized) ----
    if (wv == 0 && lane < FPB) {
        const long long m = nb + lane;
        const float ax = theta_v[m * 3 + 0];
        const float ay = theta_v[m * 3 + 1];
        const float az = theta_v[m * 3 + 2];
        const float th = theta[m];
        const float d2  = ax * ax + ay * ay + az * az;
        const float inv = rsqrtf(fmaxf(d2, 1e-24f));
        const float vx = ax * inv, vy = ay * inv, vz = az * inv;
        float s, cth;
        __sincosf(th, &s, &cth);
        const float c = 1.0f - cth;
        float* R = (float*)&sR4[lane][0];
        R[0] = 1.0f - c * (vy * vy + vz * vz);   // R00
        R[1] = -s * vz + c * (vx * vy);          // R01
        R[2] =  s * vy + c * (vx * vz);          // R02
        R[3] =  s * vz + c * (vx * vy);          // R10
        R[4] = 1.0f - c * (vx * vx + vz * vz);   // R11
        R[5] = -s * vx + c * (vy * vz);          // R12
        R[6] = -s * vy + c * (vx * vz);          // R20
        R[7] =  s * vx + c * (vy * vz);          // R21
        R[8] = 1.0f - c * (vx * vx + vy * vy);   // R22
    }

    __syncthreads();   // fill done + R published

    // ---- scatter interior: padded idx = z*81 + y*9 + x + 182 ----
    pad[wv][i0 * 81 + j0 * 9 + l0 + 182] = fv0;
    if (p1 < KP) pad[wv][i1 * 81 + j1 * 9 + l1 + 182] = fv1;

    // ---- read R (LDS broadcast, conflict-free) ----
    const float4 Ra = sR4[wv][0];
    const float4 Rb = sR4[wv][1];
    const float  R22 = ((const float*)&sR4[wv][0])[8];
    const float R00 = Ra.x, R01 = Ra.y, R02 = Ra.z, R10 = Ra.w;
    const float R11 = Rb.x, R12 = Rb.y, R20 = Rb.z, R21 = Rb.w;

    __syncthreads();   // scatter done

    const float* pw = &pad[wv][0];
    float* on = out + n * (long long)KP;

    // shifted coord: xs = x + 2 = Bi*R00 + Bj*R10 + Bl*R20 + 4, xs in [0.53, 7.47]
    // so (int)xs == floor, and ci = z0s*81 + y0s*9 + x0s (pad offset 182 cancels).
    auto sample = [&](float Bi, float Bj, float Bl) -> float {
        const float xs = fmaf(Bi, R00, fmaf(Bj, R10, fmaf(Bl, R20, 4.0f)));
        const float ys = fmaf(Bi, R01, fmaf(Bj, R11, fmaf(Bl, R21, 4.0f)));
        const float zs = fmaf(Bi, R02, fmaf(Bj, R12, fmaf(Bl, R22, 4.0f)));
        const int x0 = (int)xs, y0 = (int)ys, z0 = (int)zs;
        const float wx = __builtin_amdgcn_fractf(xs);
        const float wy = __builtin_amdgcn_fractf(ys);
        const float wz = __builtin_amdgcn_fractf(zs);
        const int ci = z0 * 81 + y0 * 9 + x0;    // in [0, 637]

        const float a00 = pw[ci],      a01 = pw[ci + 1];
        const float a10 = pw[ci + 9],  a11 = pw[ci + 10];
        const float a20 = pw[ci + 81], a21 = pw[ci + 82];
        const float a30 = pw[ci + 90], a31 = pw[ci + 91];

        const float r0 = fmaf(wx, a01 - a00, a00);
        const float r1 = fmaf(wx, a11 - a10, a10);
        const float r2 = fmaf(wx, a21 - a20, a20);
        const float r3 = fmaf(wx, a31 - a30, a30);
        const float s0 = fmaf(wy, r1 - r0, r0);
        const float s1 = fmaf(wy, r3 - r2, r2);
        return fmaf(wz, s1 - s0, s0);
    };

    on[p0] = sample((float)(i0 - 2), (float)(j0 - 2), (float)(l0 - 2));
    if (p1 < KP)
        on[p1] = sample((float)(i1 - 2), (float)(j1 - 2), (float)(l1 - 2));
}

extern "C" void kernel_launch(void* const* d_in, const int* in_sizes, int n_in,
                              void* d_out, int out_size, void* d_ws, size_t ws_size,
                              hipStream_t stream) {
    const float* vol     = (const float*)d_in[0];
    const float* theta_v = (const float*)d_in[1];
    const float* theta   = (const float*)d_in[2];
    float* out           = (float*)d_out;

    const int N = in_sizes[2];          // 262144, divisible by 8
    fastrot_kernel<<<N / FPB, FPB * 64, 0, stream>>>(vol, theta_v, theta, out);
}